// Round 1
// baseline (1708.376 us; speedup 1.0000x reference)
//
#include <hip/hip_runtime.h>

#define NN 50000
#define NE 600000
#define F  128

// ---------------- zero the accumulator (= d_out) ----------------
__global__ void k_zero(float4* __restrict__ p, int n4) {
    int i = blockIdx.x * blockDim.x + threadIdx.x;
    if (i < n4) p[i] = make_float4(0.f, 0.f, 0.f, 0.f);
}

// ---------------- COO scatter-sum SpMM ----------------
// 32 lanes per edge; each lane handles a float4 of the 128-feature row.
__global__ void k_scatter(const int* __restrict__ erow, const int* __restrict__ ecol,
                          const float* __restrict__ eval, const float* __restrict__ X,
                          float* __restrict__ agg) {
    unsigned tid = blockIdx.x * blockDim.x + threadIdx.x;
    unsigned e = tid >> 5;
    if (e >= NE) return;
    unsigned f = (tid & 31u) << 2;           // feature offset 0,4,...,124
    int   r = erow[e];
    int   c = ecol[e];
    float v = eval[e];
    float4 x = *reinterpret_cast<const float4*>(X + (size_t)c * F + f);
    float* dst = agg + (size_t)r * F + f;
    atomicAdd(dst + 0, x.x * v);
    atomicAdd(dst + 1, x.y * v);
    atomicAdd(dst + 2, x.z * v);
    atomicAdd(dst + 3, x.w * v);
}

// ---------------- in-place GEMM + ReLU: io = relu(io @ W) ----------------
// Block: 256 threads. Per chunk of 32 rows: stage rows in LDS (read-before-write
// makes in-place safe), W staged in two 64x128 k-halves. Each thread: 4 rows x
// 4 cols = 16 accumulators.
__global__ __launch_bounds__(256) void k_gemm_relu(float* __restrict__ io,
                                                   const float* __restrict__ W) {
    __shared__ float Wl[64][128];
    __shared__ float Al[32][128];
    const int tid = threadIdx.x;
    const int rg  = tid >> 5;            // row group 0..7 -> rows rg*4..rg*4+3
    const int oq  = (tid & 31) << 2;     // output quad col 0,4,...,124
    const int nch = (NN + 31) / 32;

    for (int ch = blockIdx.x; ch < nch; ch += gridDim.x) {
        const int row0 = ch * 32;
        __syncthreads();                 // prev iteration's readers done
        // stage Al: 32 rows x 128 = 1024 float4, 4 per thread
        #pragma unroll
        for (int i = 0; i < 4; ++i) {
            int idx4 = i * 256 + tid;            // float4 index 0..1023
            int r  = idx4 >> 5;                  // 32 float4 per row
            int cc = (idx4 & 31) << 2;
            int grow = row0 + r;
            float4 v = make_float4(0.f, 0.f, 0.f, 0.f);
            if (grow < NN)
                v = *reinterpret_cast<const float4*>(io + (size_t)grow * F + cc);
            *reinterpret_cast<float4*>(&Al[r][cc]) = v;
        }

        float4 acc[4];
        #pragma unroll
        for (int j = 0; j < 4; ++j) acc[j] = make_float4(0.f, 0.f, 0.f, 0.f);

        #pragma unroll
        for (int kk = 0; kk < 2; ++kk) {
            if (kk) __syncthreads();     // done computing on previous W half
            // stage W half: 64x128 = 2048 float4, 8 per thread
            #pragma unroll
            for (int i = 0; i < 8; ++i) {
                int idx4 = i * 256 + tid;
                *reinterpret_cast<float4*>(reinterpret_cast<float*>(Wl) + idx4 * 4) =
                    *reinterpret_cast<const float4*>(W + kk * 64 * F + idx4 * 4);
            }
            __syncthreads();             // Wl (and Al on kk=0) ready
            #pragma unroll
            for (int k = 0; k < 64; ++k) {
                float4 w = *reinterpret_cast<const float4*>(&Wl[k][oq]);
                float b0 = Al[rg * 4 + 0][kk * 64 + k];
                float b1 = Al[rg * 4 + 1][kk * 64 + k];
                float b2 = Al[rg * 4 + 2][kk * 64 + k];
                float b3 = Al[rg * 4 + 3][kk * 64 + k];
                acc[0].x += b0 * w.x; acc[0].y += b0 * w.y; acc[0].z += b0 * w.z; acc[0].w += b0 * w.w;
                acc[1].x += b1 * w.x; acc[1].y += b1 * w.y; acc[1].z += b1 * w.z; acc[1].w += b1 * w.w;
                acc[2].x += b2 * w.x; acc[2].y += b2 * w.y; acc[2].z += b2 * w.z; acc[2].w += b2 * w.w;
                acc[3].x += b3 * w.x; acc[3].y += b3 * w.y; acc[3].z += b3 * w.z; acc[3].w += b3 * w.w;
            }
        }
        // write ReLU'd outputs (coalesced float4 per row)
        #pragma unroll
        for (int j = 0; j < 4; ++j) {
            int grow = row0 + rg * 4 + j;
            if (grow < NN) {
                float4 a = acc[j];
                a.x = fmaxf(a.x, 0.f);
                a.y = fmaxf(a.y, 0.f);
                a.z = fmaxf(a.z, 0.f);
                a.w = fmaxf(a.w, 0.f);
                *reinterpret_cast<float4*>(io + (size_t)grow * F + oq) = a;
            }
        }
    }
}

extern "C" void kernel_launch(void* const* d_in, const int* in_sizes, int n_in,
                              void* d_out, int out_size, void* d_ws, size_t ws_size,
                              hipStream_t stream) {
    const int*   erow  = (const int*)d_in[0];
    const int*   ecol  = (const int*)d_in[1];
    const float* evals = (const float*)d_in[2];
    const float* X     = (const float*)d_in[3];
    const float* W     = (const float*)d_in[4];
    float* out = (float*)d_out;

    const int n4 = NN * F / 4;                       // 1.6M float4
    k_zero<<<(n4 + 255) / 256, 256, 0, stream>>>((float4*)out, n4);

    const int scatter_blocks = (NE * 32) / 256;      // 75000
    k_scatter<<<scatter_blocks, 256, 0, stream>>>(erow, ecol, evals, X, out);

    k_gemm_relu<<<768, 256, 0, stream>>>(out, W);
}

// Round 2
// 829.189 us; speedup vs baseline: 2.0603x; 2.0603x over previous
//
#include <hip/hip_runtime.h>

#define NN 50000
#define NE 600000
#define F  128

// ---------------- workspace layout (bytes) ----------------
// [0,        200000) : cursor  int[50000]
// [200000,   400004) : row_ptr int[50001]
// [400016,  2800016) : cols    int[600000]
// [2800016, 5200016) : vals    float[600000]
#define WS_NEEDED 5200016u

__global__ void k_zero_i(int* __restrict__ p, int n) {
    int i = blockIdx.x * blockDim.x + threadIdx.x;
    if (i < n) p[i] = 0;
}

__global__ void k_zero_f4(float4* __restrict__ p, int n4) {
    int i = blockIdx.x * blockDim.x + threadIdx.x;
    if (i < n4) p[i] = make_float4(0.f, 0.f, 0.f, 0.f);
}

// ---------------- CSR build ----------------
__global__ void k_count(const int* __restrict__ erow, int* __restrict__ cnt) {
    int e = blockIdx.x * blockDim.x + threadIdx.x;
    if (e < NE) atomicAdd(&cnt[erow[e]], 1);
}

__global__ __launch_bounds__(1024) void k_scan(const int* __restrict__ cnt,
                                               int* __restrict__ row_ptr,
                                               int* __restrict__ cursor) {
    __shared__ int wsum[16];
    __shared__ int s_carry;
    const int tid  = threadIdx.x;
    const int lane = tid & 63;
    const int wid  = tid >> 6;
    if (tid == 0) s_carry = 0;
    __syncthreads();
    for (int base = 0; base < NN; base += 1024) {
        int idx = base + tid;
        int v = (idx < NN) ? cnt[idx] : 0;
        int x = v;
        #pragma unroll
        for (int off = 1; off < 64; off <<= 1) {
            int t = __shfl_up(x, off, 64);
            if (lane >= off) x += t;
        }
        if (lane == 63) wsum[wid] = x;
        __syncthreads();
        if (wid == 0) {
            int ws = (lane < 16) ? wsum[lane] : 0;
            #pragma unroll
            for (int off = 1; off < 16; off <<= 1) {
                int t = __shfl_up(ws, off, 64);
                if (lane >= off) ws += t;
            }
            if (lane < 16) wsum[lane] = ws;   // inclusive wave totals
        }
        __syncthreads();
        int wave_excl = (wid == 0) ? 0 : wsum[wid - 1];
        int carry = s_carry;
        int excl = carry + wave_excl + (x - v);
        if (idx < NN) { row_ptr[idx] = excl; cursor[idx] = excl; }
        __syncthreads();                       // everyone done reading s_carry/wsum
        if (tid == 0) s_carry = carry + wsum[15];
        __syncthreads();
    }
    if (tid == 0) row_ptr[NN] = s_carry;       // == NE
}

__global__ void k_fill(const int* __restrict__ erow, const int* __restrict__ ecol,
                       const float* __restrict__ eval, int* __restrict__ cursor,
                       int* __restrict__ cols, float* __restrict__ vals) {
    int e = blockIdx.x * blockDim.x + threadIdx.x;
    if (e < NE) {
        int r = erow[e];
        int p = atomicAdd(&cursor[r], 1);
        cols[p] = ecol[e];
        vals[p] = eval[e];
    }
}

// ---------------- atomic-free aggregation: one wave per node ----------------
__global__ __launch_bounds__(256) void k_agg(const int* __restrict__ row_ptr,
                                             const int* __restrict__ cols,
                                             const float* __restrict__ vals,
                                             const float* __restrict__ X,
                                             float* __restrict__ agg) {
    const int wid  = threadIdx.x >> 6;
    const int lane = threadIdx.x & 63;
    const int node = blockIdx.x * 4 + wid;
    if (node >= NN) return;
    const int p0 = row_ptr[node];
    const int p1 = row_ptr[node + 1];
    const float* Xl = X + lane * 2;
    float2 a0 = make_float2(0.f, 0.f);
    float2 a1 = make_float2(0.f, 0.f);
    int i = p0;
    for (; i + 2 <= p1; i += 2) {
        int   c0 = cols[i],   c1 = cols[i + 1];
        float v0 = vals[i],   v1 = vals[i + 1];
        float2 x0 = *reinterpret_cast<const float2*>(Xl + (size_t)c0 * F);
        float2 x1 = *reinterpret_cast<const float2*>(Xl + (size_t)c1 * F);
        a0.x += x0.x * v0; a0.y += x0.y * v0;
        a1.x += x1.x * v1; a1.y += x1.y * v1;
    }
    if (i < p1) {
        int c = cols[i]; float v = vals[i];
        float2 x = *reinterpret_cast<const float2*>(Xl + (size_t)c * F);
        a0.x += x.x * v; a0.y += x.y * v;
    }
    float2 r = make_float2(a0.x + a1.x, a0.y + a1.y);
    *reinterpret_cast<float2*>(agg + (size_t)node * F + lane * 2) = r;
}

// ---------------- legacy atomic scatter (ws-too-small fallback) ----------------
__global__ void k_scatter(const int* __restrict__ erow, const int* __restrict__ ecol,
                          const float* __restrict__ eval, const float* __restrict__ X,
                          float* __restrict__ agg) {
    unsigned tid = blockIdx.x * blockDim.x + threadIdx.x;
    unsigned e = tid >> 5;
    if (e >= NE) return;
    unsigned f = (tid & 31u) << 2;
    int   r = erow[e];
    int   c = ecol[e];
    float v = eval[e];
    float4 x = *reinterpret_cast<const float4*>(X + (size_t)c * F + f);
    float* dst = agg + (size_t)r * F + f;
    atomicAdd(dst + 0, x.x * v);
    atomicAdd(dst + 1, x.y * v);
    atomicAdd(dst + 2, x.z * v);
    atomicAdd(dst + 3, x.w * v);
}

// ---------------- in-place GEMM + ReLU: io = relu(io @ W) ----------------
#define FMA4(ACC, AS, WV) \
    ACC.x += (AS) * WV.x; ACC.y += (AS) * WV.y; ACC.z += (AS) * WV.z; ACC.w += (AS) * WV.w;

__global__ __launch_bounds__(256) void k_gemm_relu(float* __restrict__ io,
                                                   const float* __restrict__ W) {
    __shared__ float Wl[64][128];   // 32 KB: one K-half of W
    __shared__ float Al[32][128];   // 16 KB: 32 A rows
    const int tid = threadIdx.x;
    const int rg  = tid >> 5;             // row group: rows rg*4 .. rg*4+3
    const int oq  = (tid & 31) << 2;      // output cols oq .. oq+3
    const int nch = (NN + 31) / 32;

    for (int ch = blockIdx.x; ch < nch; ch += gridDim.x) {
        const int row0 = ch * 32;
        __syncthreads();                  // prev chunk's readers done
        #pragma unroll
        for (int i = 0; i < 4; ++i) {
            int idx4 = i * 256 + tid;
            int r  = idx4 >> 5;
            int cc = (idx4 & 31) << 2;
            int grow = row0 + r;
            float4 v = make_float4(0.f, 0.f, 0.f, 0.f);
            if (grow < NN)
                v = *reinterpret_cast<const float4*>(io + (size_t)grow * F + cc);
            *reinterpret_cast<float4*>(&Al[r][cc]) = v;
        }

        float4 acc[4];
        #pragma unroll
        for (int j = 0; j < 4; ++j) acc[j] = make_float4(0.f, 0.f, 0.f, 0.f);

        #pragma unroll
        for (int kk = 0; kk < 2; ++kk) {
            if (kk) __syncthreads();
            #pragma unroll
            for (int i = 0; i < 8; ++i) {
                int idx4 = i * 256 + tid;
                *reinterpret_cast<float4*>(reinterpret_cast<float*>(Wl) + idx4 * 4) =
                    *reinterpret_cast<const float4*>(W + kk * 64 * F + idx4 * 4);
            }
            __syncthreads();
            #pragma unroll
            for (int k4 = 0; k4 < 64; k4 += 4) {
                const int kb = kk * 64 + k4;
                float4 a0 = *reinterpret_cast<const float4*>(&Al[rg * 4 + 0][kb]);
                float4 a1 = *reinterpret_cast<const float4*>(&Al[rg * 4 + 1][kb]);
                float4 a2 = *reinterpret_cast<const float4*>(&Al[rg * 4 + 2][kb]);
                float4 a3 = *reinterpret_cast<const float4*>(&Al[rg * 4 + 3][kb]);
                float4 w0 = *reinterpret_cast<const float4*>(&Wl[k4 + 0][oq]);
                float4 w1 = *reinterpret_cast<const float4*>(&Wl[k4 + 1][oq]);
                float4 w2 = *reinterpret_cast<const float4*>(&Wl[k4 + 2][oq]);
                float4 w3 = *reinterpret_cast<const float4*>(&Wl[k4 + 3][oq]);
                FMA4(acc[0], a0.x, w0) FMA4(acc[0], a0.y, w1) FMA4(acc[0], a0.z, w2) FMA4(acc[0], a0.w, w3)
                FMA4(acc[1], a1.x, w0) FMA4(acc[1], a1.y, w1) FMA4(acc[1], a1.z, w2) FMA4(acc[1], a1.w, w3)
                FMA4(acc[2], a2.x, w0) FMA4(acc[2], a2.y, w1) FMA4(acc[2], a2.z, w2) FMA4(acc[2], a2.w, w3)
                FMA4(acc[3], a3.x, w0) FMA4(acc[3], a3.y, w1) FMA4(acc[3], a3.z, w2) FMA4(acc[3], a3.w, w3)
            }
        }
        #pragma unroll
        for (int j = 0; j < 4; ++j) {
            int grow = row0 + rg * 4 + j;
            if (grow < NN) {
                float4 a = acc[j];
                a.x = fmaxf(a.x, 0.f);
                a.y = fmaxf(a.y, 0.f);
                a.z = fmaxf(a.z, 0.f);
                a.w = fmaxf(a.w, 0.f);
                *reinterpret_cast<float4*>(io + (size_t)grow * F + oq) = a;
            }
        }
    }
}

extern "C" void kernel_launch(void* const* d_in, const int* in_sizes, int n_in,
                              void* d_out, int out_size, void* d_ws, size_t ws_size,
                              hipStream_t stream) {
    const int*   erow  = (const int*)d_in[0];
    const int*   ecol  = (const int*)d_in[1];
    const float* evals = (const float*)d_in[2];
    const float* X     = (const float*)d_in[3];
    const float* W     = (const float*)d_in[4];
    float* out = (float*)d_out;

    if (ws_size >= WS_NEEDED) {
        char* ws = (char*)d_ws;
        int*   cursor  = (int*)(ws + 0);
        int*   row_ptr = (int*)(ws + 200000);
        int*   cols    = (int*)(ws + 400016);
        float* vals    = (float*)(ws + 2800016);

        k_zero_i<<<(NN + 255) / 256, 256, 0, stream>>>(cursor, NN);
        k_count<<<(NE + 255) / 256, 256, 0, stream>>>(erow, cursor);
        // scan reads counts from `cursor`, writes row_ptr and resets cursor to starts
        k_scan<<<1, 1024, 0, stream>>>(cursor, row_ptr, cursor);
        k_fill<<<(NE + 255) / 256, 256, 0, stream>>>(erow, ecol, evals, cursor, cols, vals);
        k_agg<<<(NN + 3) / 4, 256, 0, stream>>>(row_ptr, cols, vals, X, out);
    } else {
        const int n4 = NN * F / 4;
        k_zero_f4<<<(n4 + 255) / 256, 256, 0, stream>>>((float4*)out, n4);
        k_scatter<<<(NE * 32) / 256, 256, 0, stream>>>(erow, ecol, evals, X, out);
    }
    k_gemm_relu<<<768, 256, 0, stream>>>(out, W);
}

// Round 3
// 206.252 us; speedup vs baseline: 8.2830x; 4.0203x over previous
//
#include <hip/hip_runtime.h>

#define NN 50000
#define NE 600000
#define F  128

// ---------------- workspace layout (bytes) ----------------
// [0,        200000) : cursor  int[50000]
// [200000,   400004) : row_ptr int[50001]
// [400016,  2800016) : cols    int[600000]
// [2800016, 5200016) : vals    float[600000]
#define WS_NEEDED 5200016u

__global__ void k_zero_i(int* __restrict__ p, int n) {
    int i = blockIdx.x * blockDim.x + threadIdx.x;
    if (i < n) p[i] = 0;
}

__global__ void k_zero_f4(float4* __restrict__ p, int n4) {
    int i = blockIdx.x * blockDim.x + threadIdx.x;
    if (i < n4) p[i] = make_float4(0.f, 0.f, 0.f, 0.f);
}

// ---------------- CSR build ----------------
__global__ void k_count(const int* __restrict__ erow, int* __restrict__ cnt) {
    int e = blockIdx.x * blockDim.x + threadIdx.x;
    if (e < NE) atomicAdd(&cnt[erow[e]], 1);
}

__global__ __launch_bounds__(1024) void k_scan(const int* __restrict__ cnt,
                                               int* __restrict__ row_ptr,
                                               int* __restrict__ cursor) {
    __shared__ int wsum[16];
    __shared__ int s_carry;
    const int tid  = threadIdx.x;
    const int lane = tid & 63;
    const int wid  = tid >> 6;
    if (tid == 0) s_carry = 0;
    __syncthreads();
    for (int base = 0; base < NN; base += 1024) {
        int idx = base + tid;
        int v = (idx < NN) ? cnt[idx] : 0;
        int x = v;
        #pragma unroll
        for (int off = 1; off < 64; off <<= 1) {
            int t = __shfl_up(x, off, 64);
            if (lane >= off) x += t;
        }
        if (lane == 63) wsum[wid] = x;
        __syncthreads();
        if (wid == 0) {
            int ws = (lane < 16) ? wsum[lane] : 0;
            #pragma unroll
            for (int off = 1; off < 16; off <<= 1) {
                int t = __shfl_up(ws, off, 64);
                if (lane >= off) ws += t;
            }
            if (lane < 16) wsum[lane] = ws;   // inclusive wave totals
        }
        __syncthreads();
        int wave_excl = (wid == 0) ? 0 : wsum[wid - 1];
        int carry = s_carry;
        int excl = carry + wave_excl + (x - v);
        if (idx < NN) { row_ptr[idx] = excl; cursor[idx] = excl; }
        __syncthreads();
        if (tid == 0) s_carry = carry + wsum[15];
        __syncthreads();
    }
    if (tid == 0) row_ptr[NN] = s_carry;       // == NE
}

__global__ void k_fill(const int* __restrict__ erow, const int* __restrict__ ecol,
                       const float* __restrict__ eval, int* __restrict__ cursor,
                       int* __restrict__ cols, float* __restrict__ vals) {
    int e = blockIdx.x * blockDim.x + threadIdx.x;
    if (e < NE) {
        int r = erow[e];
        int p = atomicAdd(&cursor[r], 1);
        cols[p] = ecol[e];
        vals[p] = eval[e];
    }
}

// ---------------- atomic-free aggregation: one wave per node ----------------
__global__ __launch_bounds__(256) void k_agg(const int* __restrict__ row_ptr,
                                             const int* __restrict__ cols,
                                             const float* __restrict__ vals,
                                             const float* __restrict__ X,
                                             float* __restrict__ agg) {
    const int wid  = threadIdx.x >> 6;
    const int lane = threadIdx.x & 63;
    const int node = blockIdx.x * 4 + wid;
    if (node >= NN) return;
    const int p0 = row_ptr[node];
    const int p1 = row_ptr[node + 1];
    const float* Xl = X + lane * 2;
    float2 a0 = make_float2(0.f, 0.f);
    float2 a1 = make_float2(0.f, 0.f);
    int i = p0;
    for (; i + 2 <= p1; i += 2) {
        int   c0 = cols[i],   c1 = cols[i + 1];
        float v0 = vals[i],   v1 = vals[i + 1];
        float2 x0 = *reinterpret_cast<const float2*>(Xl + (size_t)c0 * F);
        float2 x1 = *reinterpret_cast<const float2*>(Xl + (size_t)c1 * F);
        a0.x += x0.x * v0; a0.y += x0.y * v0;
        a1.x += x1.x * v1; a1.y += x1.y * v1;
    }
    if (i < p1) {
        int c = cols[i]; float v = vals[i];
        float2 x = *reinterpret_cast<const float2*>(Xl + (size_t)c * F);
        a0.x += x.x * v; a0.y += x.y * v;
    }
    float2 r = make_float2(a0.x + a1.x, a0.y + a1.y);
    *reinterpret_cast<float2*>(agg + (size_t)node * F + lane * 2) = r;
}

// ---------------- legacy atomic scatter (ws-too-small fallback) ----------------
__global__ void k_scatter(const int* __restrict__ erow, const int* __restrict__ ecol,
                          const float* __restrict__ eval, const float* __restrict__ X,
                          float* __restrict__ agg) {
    unsigned tid = blockIdx.x * blockDim.x + threadIdx.x;
    unsigned e = tid >> 5;
    if (e >= NE) return;
    unsigned f = (tid & 31u) << 2;
    int   r = erow[e];
    int   c = ecol[e];
    float v = eval[e];
    float4 x = *reinterpret_cast<const float4*>(X + (size_t)c * F + f);
    float* dst = agg + (size_t)r * F + f;
    atomicAdd(dst + 0, x.x * v);
    atomicAdd(dst + 1, x.y * v);
    atomicAdd(dst + 2, x.z * v);
    atomicAdd(dst + 3, x.w * v);
}

// ---------------- in-place GEMM + ReLU: io = relu(io @ W) ----------------
// One 64-row chunk per block. Per thread: 8 rows x 4 cols = 32 accumulators.
// W staged in two 64x128 halves (once each). Small live set: no spills.
#define FMA4(ACC, AS, WV) \
    ACC.x += (AS) * WV.x; ACC.y += (AS) * WV.y; ACC.z += (AS) * WV.z; ACC.w += (AS) * WV.w;

__global__ __launch_bounds__(256) void k_gemm_relu(float* __restrict__ io,
                                                   const float* __restrict__ W) {
    __shared__ float Wl[64][128];   // 32 KB: one K-half of W
    __shared__ float Al[64][128];   // 32 KB: 64 A rows
    const int tid = threadIdx.x;
    const int rg  = tid >> 5;             // row group: rows rg*8 .. rg*8+7
    const int oq  = (tid & 31) << 2;      // output cols oq .. oq+3
    const int row0 = blockIdx.x * 64;

    // stage Al: 64 rows x 128 = 2048 float4, 8 per thread
    #pragma unroll
    for (int i = 0; i < 8; ++i) {
        int idx4 = i * 256 + tid;
        int r  = idx4 >> 5;
        int cc = (idx4 & 31) << 2;
        int grow = row0 + r;
        float4 v = make_float4(0.f, 0.f, 0.f, 0.f);
        if (grow < NN)
            v = *reinterpret_cast<const float4*>(io + (size_t)grow * F + cc);
        *reinterpret_cast<float4*>(&Al[r][cc]) = v;
    }

    float4 acc[8];
    #pragma unroll
    for (int j = 0; j < 8; ++j) acc[j] = make_float4(0.f, 0.f, 0.f, 0.f);

    for (int kk = 0; kk < 2; ++kk) {
        if (kk) __syncthreads();          // done computing on previous W half
        #pragma unroll
        for (int i = 0; i < 8; ++i) {
            int idx4 = i * 256 + tid;
            *reinterpret_cast<float4*>(reinterpret_cast<float*>(Wl) + idx4 * 4) =
                *reinterpret_cast<const float4*>(W + kk * 64 * F + idx4 * 4);
        }
        __syncthreads();                  // Wl (and Al on kk=0) ready
        #pragma unroll 2
        for (int k4 = 0; k4 < 64; k4 += 4) {
            float4 w0 = *reinterpret_cast<const float4*>(&Wl[k4 + 0][oq]);
            float4 w1 = *reinterpret_cast<const float4*>(&Wl[k4 + 1][oq]);
            float4 w2 = *reinterpret_cast<const float4*>(&Wl[k4 + 2][oq]);
            float4 w3 = *reinterpret_cast<const float4*>(&Wl[k4 + 3][oq]);
            #pragma unroll
            for (int r = 0; r < 8; ++r) {
                float4 a = *reinterpret_cast<const float4*>(&Al[rg * 8 + r][kk * 64 + k4]);
                FMA4(acc[r], a.x, w0)
                FMA4(acc[r], a.y, w1)
                FMA4(acc[r], a.z, w2)
                FMA4(acc[r], a.w, w3)
            }
        }
    }
    // write ReLU'd outputs (512B contiguous per 32-lane group per row)
    #pragma unroll
    for (int r = 0; r < 8; ++r) {
        int grow = row0 + rg * 8 + r;
        if (grow < NN) {
            float4 a = acc[r];
            a.x = fmaxf(a.x, 0.f);
            a.y = fmaxf(a.y, 0.f);
            a.z = fmaxf(a.z, 0.f);
            a.w = fmaxf(a.w, 0.f);
            *reinterpret_cast<float4*>(io + (size_t)grow * F + oq) = a;
        }
    }
}

extern "C" void kernel_launch(void* const* d_in, const int* in_sizes, int n_in,
                              void* d_out, int out_size, void* d_ws, size_t ws_size,
                              hipStream_t stream) {
    const int*   erow  = (const int*)d_in[0];
    const int*   ecol  = (const int*)d_in[1];
    const float* evals = (const float*)d_in[2];
    const float* X     = (const float*)d_in[3];
    const float* W     = (const float*)d_in[4];
    float* out = (float*)d_out;

    if (ws_size >= WS_NEEDED) {
        char* ws = (char*)d_ws;
        int*   cursor  = (int*)(ws + 0);
        int*   row_ptr = (int*)(ws + 200000);
        int*   cols    = (int*)(ws + 400016);
        float* vals    = (float*)(ws + 2800016);

        k_zero_i<<<(NN + 255) / 256, 256, 0, stream>>>(cursor, NN);
        k_count<<<(NE + 255) / 256, 256, 0, stream>>>(erow, cursor);
        k_scan<<<1, 1024, 0, stream>>>(cursor, row_ptr, cursor);
        k_fill<<<(NE + 255) / 256, 256, 0, stream>>>(erow, ecol, evals, cursor, cols, vals);
        k_agg<<<(NN + 3) / 4, 256, 0, stream>>>(row_ptr, cols, vals, X, out);
    } else {
        const int n4 = NN * F / 4;
        k_zero_f4<<<(n4 + 255) / 256, 256, 0, stream>>>((float4*)out, n4);
        k_scatter<<<(NE * 32) / 256, 256, 0, stream>>>(erow, ecol, evals, X, out);
    }
    k_gemm_relu<<<(NN + 63) / 64, 256, 0, stream>>>(out, W);
}

// Round 4
// 158.121 us; speedup vs baseline: 10.8042x; 1.3044x over previous
//
#include <hip/hip_runtime.h>

#define NN 50000
#define NE 600000
#define F  128

// ---------------- workspace layout (bytes) ----------------
// [0,       200000) : cursor/counts  int[50000]
// [200000,  400004) : row_ptr        int[50001]
// [400016,  400800) : bsum int[196]   (dead before pairs is written)
// [400016, 5200016) : pairs int2[600000] {col, val_bits}
#define WS_NEEDED 5200016u
#define NB_SCAN 196           // ceil(50000/256)

__global__ void k_zero_i(int* __restrict__ p, int n) {
    int i = blockIdx.x * blockDim.x + threadIdx.x;
    if (i < n) p[i] = 0;
}

// ---------------- CSR build ----------------
__global__ void k_count(const int* __restrict__ erow, int* __restrict__ cnt) {
    int e = blockIdx.x * blockDim.x + threadIdx.x;
    if (e < NE) atomicAdd(&cnt[erow[e]], 1);
}

__device__ __forceinline__ int wave_incl_scan(int x, int lane) {
    #pragma unroll
    for (int off = 1; off < 64; off <<= 1) {
        int t = __shfl_up(x, off, 64);
        if (lane >= off) x += t;
    }
    return x;
}

// pass 1: per-block sum of 256 counts
__global__ __launch_bounds__(256) void k_bsum(const int* __restrict__ cnt,
                                              int* __restrict__ bsum) {
    __shared__ int ws4[4];
    int idx  = blockIdx.x * 256 + threadIdx.x;
    int lane = threadIdx.x & 63, wid = threadIdx.x >> 6;
    int v = (idx < NN) ? cnt[idx] : 0;
    #pragma unroll
    for (int off = 32; off; off >>= 1) v += __shfl_down(v, off, 64);
    if (lane == 0) ws4[wid] = v;
    __syncthreads();
    if (threadIdx.x == 0) bsum[blockIdx.x] = ws4[0] + ws4[1] + ws4[2] + ws4[3];
}

// pass 2: exclusive scan of the 196 block sums (single tiny block)
__global__ __launch_bounds__(256) void k_scan_bsums(int* __restrict__ bsum) {
    __shared__ int wtot[4];
    int lane = threadIdx.x & 63, wid = threadIdx.x >> 6;
    int v = (threadIdx.x < NB_SCAN) ? bsum[threadIdx.x] : 0;
    int x = wave_incl_scan(v, lane);
    if (lane == 63) wtot[wid] = x;
    __syncthreads();
    int prefix = 0;
    #pragma unroll
    for (int w = 0; w < 4; ++w) if (w < wid) prefix += wtot[w];
    __syncthreads();
    if (threadIdx.x < NB_SCAN) bsum[threadIdx.x] = prefix + x - v;
}

// pass 3: block-local exclusive scan + block offset -> row_ptr, cursor
// NOTE: cnt and cursor alias (read idx before write idx, same thread) — no __restrict__
__global__ __launch_bounds__(256) void k_scan_final(const int* cnt,
                                                    const int* __restrict__ bsum,
                                                    int* __restrict__ row_ptr,
                                                    int* cursor) {
    __shared__ int wtot[4];
    int idx  = blockIdx.x * 256 + threadIdx.x;
    int lane = threadIdx.x & 63, wid = threadIdx.x >> 6;
    int v = (idx < NN) ? cnt[idx] : 0;
    int x = wave_incl_scan(v, lane);
    if (lane == 63) wtot[wid] = x;
    __syncthreads();
    int prefix = bsum[blockIdx.x];
    #pragma unroll
    for (int w = 0; w < 4; ++w) if (w < wid) prefix += wtot[w];
    int excl = prefix + x - v;
    if (idx < NN) { row_ptr[idx] = excl; cursor[idx] = excl; }
    if (idx == 0) row_ptr[NN] = NE;
}

__global__ void k_fill(const int* __restrict__ erow, const int* __restrict__ ecol,
                       const float* __restrict__ eval, int* __restrict__ cursor,
                       int2* __restrict__ pairs) {
    int e = blockIdx.x * blockDim.x + threadIdx.x;
    if (e < NE) {
        int r = erow[e];
        int p = atomicAdd(&cursor[r], 1);
        pairs[p] = make_int2(ecol[e], __float_as_int(eval[e]));
    }
}

// ---------------- atomic-free aggregation: one wave per node, 4-edge ILP ----------------
__global__ __launch_bounds__(256) void k_agg(const int* __restrict__ row_ptr,
                                             const int2* __restrict__ pairs,
                                             const float* __restrict__ X,
                                             float* __restrict__ agg) {
    const int wid  = threadIdx.x >> 6;
    const int lane = threadIdx.x & 63;
    const int node = blockIdx.x * 4 + wid;
    if (node >= NN) return;
    const int p0 = row_ptr[node];
    const int p1 = row_ptr[node + 1];
    const float* Xl = X + lane * 2;
    float2 a0 = make_float2(0.f, 0.f), a1 = a0, a2 = a0, a3 = a0;
    int i = p0;
    for (; i + 4 <= p1; i += 4) {
        int2 e0 = pairs[i], e1 = pairs[i + 1], e2 = pairs[i + 2], e3 = pairs[i + 3];
        float2 x0 = *reinterpret_cast<const float2*>(Xl + (size_t)e0.x * F);
        float2 x1 = *reinterpret_cast<const float2*>(Xl + (size_t)e1.x * F);
        float2 x2 = *reinterpret_cast<const float2*>(Xl + (size_t)e2.x * F);
        float2 x3 = *reinterpret_cast<const float2*>(Xl + (size_t)e3.x * F);
        float v0 = __int_as_float(e0.y), v1 = __int_as_float(e1.y);
        float v2 = __int_as_float(e2.y), v3 = __int_as_float(e3.y);
        a0.x += x0.x * v0; a0.y += x0.y * v0;
        a1.x += x1.x * v1; a1.y += x1.y * v1;
        a2.x += x2.x * v2; a2.y += x2.y * v2;
        a3.x += x3.x * v3; a3.y += x3.y * v3;
    }
    for (; i < p1; ++i) {
        int2 e = pairs[i];
        float v = __int_as_float(e.y);
        float2 x = *reinterpret_cast<const float2*>(Xl + (size_t)e.x * F);
        a0.x += x.x * v; a0.y += x.y * v;
    }
    float2 r = make_float2((a0.x + a1.x) + (a2.x + a3.x),
                           (a0.y + a1.y) + (a2.y + a3.y));
    *reinterpret_cast<float2*>(agg + (size_t)node * F + lane * 2) = r;
}

// ---------------- in-place GEMM + ReLU: io = relu(io @ W) ----------------
#define FMA4(ACC, AS, WV) \
    ACC.x += (AS) * WV.x; ACC.y += (AS) * WV.y; ACC.z += (AS) * WV.z; ACC.w += (AS) * WV.w;

__global__ __launch_bounds__(256) void k_gemm_relu(float* __restrict__ io,
                                                   const float* __restrict__ W) {
    __shared__ float Wl[64][128];   // 32 KB: one K-half of W
    __shared__ float Al[64][128];   // 32 KB: 64 A rows
    const int tid = threadIdx.x;
    const int rg  = tid >> 5;             // row group: rows rg*8 .. rg*8+7
    const int oq  = (tid & 31) << 2;      // output cols oq .. oq+3
    const int row0 = blockIdx.x * 64;

    #pragma unroll
    for (int i = 0; i < 8; ++i) {
        int idx4 = i * 256 + tid;
        int r  = idx4 >> 5;
        int cc = (idx4 & 31) << 2;
        int grow = row0 + r;
        float4 v = make_float4(0.f, 0.f, 0.f, 0.f);
        if (grow < NN)
            v = *reinterpret_cast<const float4*>(io + (size_t)grow * F + cc);
        *reinterpret_cast<float4*>(&Al[r][cc]) = v;
    }

    float4 acc[8];
    #pragma unroll
    for (int j = 0; j < 8; ++j) acc[j] = make_float4(0.f, 0.f, 0.f, 0.f);

    for (int kk = 0; kk < 2; ++kk) {
        if (kk) __syncthreads();
        #pragma unroll
        for (int i = 0; i < 8; ++i) {
            int idx4 = i * 256 + tid;
            *reinterpret_cast<float4*>(reinterpret_cast<float*>(Wl) + idx4 * 4) =
                *reinterpret_cast<const float4*>(W + kk * 64 * F + idx4 * 4);
        }
        __syncthreads();
        #pragma unroll 2
        for (int k4 = 0; k4 < 64; k4 += 4) {
            float4 w0 = *reinterpret_cast<const float4*>(&Wl[k4 + 0][oq]);
            float4 w1 = *reinterpret_cast<const float4*>(&Wl[k4 + 1][oq]);
            float4 w2 = *reinterpret_cast<const float4*>(&Wl[k4 + 2][oq]);
            float4 w3 = *reinterpret_cast<const float4*>(&Wl[k4 + 3][oq]);
            #pragma unroll
            for (int r = 0; r < 8; ++r) {
                float4 a = *reinterpret_cast<const float4*>(&Al[rg * 8 + r][kk * 64 + k4]);
                FMA4(acc[r], a.x, w0)
                FMA4(acc[r], a.y, w1)
                FMA4(acc[r], a.z, w2)
                FMA4(acc[r], a.w, w3)
            }
        }
    }
    #pragma unroll
    for (int r = 0; r < 8; ++r) {
        int grow = row0 + rg * 8 + r;
        if (grow < NN) {
            float4 a = acc[r];
            a.x = fmaxf(a.x, 0.f);
            a.y = fmaxf(a.y, 0.f);
            a.z = fmaxf(a.z, 0.f);
            a.w = fmaxf(a.w, 0.f);
            *reinterpret_cast<float4*>(io + (size_t)grow * F + oq) = a;
        }
    }
}

// ---------------- legacy atomic scatter (ws-too-small fallback) ----------------
__global__ void k_zero_f4(float4* __restrict__ p, int n4) {
    int i = blockIdx.x * blockDim.x + threadIdx.x;
    if (i < n4) p[i] = make_float4(0.f, 0.f, 0.f, 0.f);
}

__global__ void k_scatter(const int* __restrict__ erow, const int* __restrict__ ecol,
                          const float* __restrict__ eval, const float* __restrict__ X,
                          float* __restrict__ agg) {
    unsigned tid = blockIdx.x * blockDim.x + threadIdx.x;
    unsigned e = tid >> 5;
    if (e >= NE) return;
    unsigned f = (tid & 31u) << 2;
    int   r = erow[e];
    int   c = ecol[e];
    float v = eval[e];
    float4 x = *reinterpret_cast<const float4*>(X + (size_t)c * F + f);
    float* dst = agg + (size_t)r * F + f;
    atomicAdd(dst + 0, x.x * v);
    atomicAdd(dst + 1, x.y * v);
    atomicAdd(dst + 2, x.z * v);
    atomicAdd(dst + 3, x.w * v);
}

extern "C" void kernel_launch(void* const* d_in, const int* in_sizes, int n_in,
                              void* d_out, int out_size, void* d_ws, size_t ws_size,
                              hipStream_t stream) {
    const int*   erow  = (const int*)d_in[0];
    const int*   ecol  = (const int*)d_in[1];
    const float* evals = (const float*)d_in[2];
    const float* X     = (const float*)d_in[3];
    const float* W     = (const float*)d_in[4];
    float* out = (float*)d_out;

    if (ws_size >= WS_NEEDED) {
        char* ws = (char*)d_ws;
        int*   cursor  = (int*)(ws + 0);
        int*   row_ptr = (int*)(ws + 200000);
        int*   bsum    = (int*)(ws + 400016);
        int2*  pairs   = (int2*)(ws + 400016);   // overlaps bsum: bsum dead before fill

        k_zero_i<<<(NN + 255) / 256, 256, 0, stream>>>(cursor, NN);
        k_count<<<(NE + 255) / 256, 256, 0, stream>>>(erow, cursor);
        k_bsum<<<NB_SCAN, 256, 0, stream>>>(cursor, bsum);
        k_scan_bsums<<<1, 256, 0, stream>>>(bsum);
        k_scan_final<<<NB_SCAN, 256, 0, stream>>>(cursor, bsum, row_ptr, cursor);
        k_fill<<<(NE + 255) / 256, 256, 0, stream>>>(erow, ecol, evals, cursor, pairs);
        k_agg<<<(NN + 3) / 4, 256, 0, stream>>>(row_ptr, pairs, X, out);
    } else {
        const int n4 = NN * F / 4;
        k_zero_f4<<<(n4 + 255) / 256, 256, 0, stream>>>((float4*)out, n4);
        k_scatter<<<(NE * 32) / 256, 256, 0, stream>>>(erow, ecol, evals, X, out);
    }
    k_gemm_relu<<<(NN + 63) / 64, 256, 0, stream>>>(out, W);
}

// Round 5
// 144.213 us; speedup vs baseline: 11.8462x; 1.0964x over previous
//
#include <hip/hip_runtime.h>
#include <hip/hip_fp16.h>

#define NN 50000
#define NE 600000
#define F  128

// ---------------- workspace layout (bytes) ----------------
// [0,       200000) : cursor/counts  int[50000]
// [200000,  400004) : row_ptr        int[50001]
// [400016,  400800) : bsum int[196]   (dead before pairs is written)
// [400016, 5200016) : pairs int2[600000] {col, val_bits}
// [5200016,18000016): XW __half[50000*128]   (fused path only)
#define WS_CSR   5200016u
#define WS_FUSED 18000016u
#define NB_SCAN 196           // ceil(50000/256)

__global__ void k_zero_i(int* __restrict__ p, int n) {
    int i = blockIdx.x * blockDim.x + threadIdx.x;
    if (i < n) p[i] = 0;
}

// ---------------- CSR build ----------------
__global__ void k_count(const int* __restrict__ erow, int* __restrict__ cnt) {
    int e = blockIdx.x * blockDim.x + threadIdx.x;
    if (e < NE) atomicAdd(&cnt[erow[e]], 1);
}

__device__ __forceinline__ int wave_incl_scan(int x, int lane) {
    #pragma unroll
    for (int off = 1; off < 64; off <<= 1) {
        int t = __shfl_up(x, off, 64);
        if (lane >= off) x += t;
    }
    return x;
}

__global__ __launch_bounds__(256) void k_bsum(const int* __restrict__ cnt,
                                              int* __restrict__ bsum) {
    __shared__ int ws4[4];
    int idx  = blockIdx.x * 256 + threadIdx.x;
    int lane = threadIdx.x & 63, wid = threadIdx.x >> 6;
    int v = (idx < NN) ? cnt[idx] : 0;
    #pragma unroll
    for (int off = 32; off; off >>= 1) v += __shfl_down(v, off, 64);
    if (lane == 0) ws4[wid] = v;
    __syncthreads();
    if (threadIdx.x == 0) bsum[blockIdx.x] = ws4[0] + ws4[1] + ws4[2] + ws4[3];
}

__global__ __launch_bounds__(256) void k_scan_bsums(int* __restrict__ bsum) {
    __shared__ int wtot[4];
    int lane = threadIdx.x & 63, wid = threadIdx.x >> 6;
    int v = (threadIdx.x < NB_SCAN) ? bsum[threadIdx.x] : 0;
    int x = wave_incl_scan(v, lane);
    if (lane == 63) wtot[wid] = x;
    __syncthreads();
    int prefix = 0;
    #pragma unroll
    for (int w = 0; w < 4; ++w) if (w < wid) prefix += wtot[w];
    __syncthreads();
    if (threadIdx.x < NB_SCAN) bsum[threadIdx.x] = prefix + x - v;
}

// cnt and cursor alias (read idx before write idx, same thread) — no __restrict__
__global__ __launch_bounds__(256) void k_scan_final(const int* cnt,
                                                    const int* __restrict__ bsum,
                                                    int* __restrict__ row_ptr,
                                                    int* cursor) {
    __shared__ int wtot[4];
    int idx  = blockIdx.x * 256 + threadIdx.x;
    int lane = threadIdx.x & 63, wid = threadIdx.x >> 6;
    int v = (idx < NN) ? cnt[idx] : 0;
    int x = wave_incl_scan(v, lane);
    if (lane == 63) wtot[wid] = x;
    __syncthreads();
    int prefix = bsum[blockIdx.x];
    #pragma unroll
    for (int w = 0; w < 4; ++w) if (w < wid) prefix += wtot[w];
    int excl = prefix + x - v;
    if (idx < NN) { row_ptr[idx] = excl; cursor[idx] = excl; }
    if (idx == 0) row_ptr[NN] = NE;
}

__global__ void k_fill(const int* __restrict__ erow, const int* __restrict__ ecol,
                       const float* __restrict__ eval, int* __restrict__ cursor,
                       int2* __restrict__ pairs) {
    int e = blockIdx.x * blockDim.x + threadIdx.x;
    if (e < NE) {
        int r = erow[e];
        int p = atomicAdd(&cursor[r], 1);
        pairs[p] = make_int2(ecol[e], __float_as_int(eval[e]));
    }
}

// ---------------- XW = X @ W, f32 -> fp16 ----------------
#define FMA4(ACC, AS, WV) \
    ACC.x += (AS) * WV.x; ACC.y += (AS) * WV.y; ACC.z += (AS) * WV.z; ACC.w += (AS) * WV.w;

__global__ __launch_bounds__(256) void k_gemm_xw(const float* __restrict__ X,
                                                 const float* __restrict__ W,
                                                 __half* __restrict__ XW) {
    __shared__ float Wl[64][128];
    __shared__ float Al[64][128];
    const int tid = threadIdx.x;
    const int rg  = tid >> 5;
    const int oq  = (tid & 31) << 2;
    const int row0 = blockIdx.x * 64;

    #pragma unroll
    for (int i = 0; i < 8; ++i) {
        int idx4 = i * 256 + tid;
        int r  = idx4 >> 5;
        int cc = (idx4 & 31) << 2;
        int grow = row0 + r;
        float4 v = make_float4(0.f, 0.f, 0.f, 0.f);
        if (grow < NN)
            v = *reinterpret_cast<const float4*>(X + (size_t)grow * F + cc);
        *reinterpret_cast<float4*>(&Al[r][cc]) = v;
    }

    float4 acc[8];
    #pragma unroll
    for (int j = 0; j < 8; ++j) acc[j] = make_float4(0.f, 0.f, 0.f, 0.f);

    for (int kk = 0; kk < 2; ++kk) {
        if (kk) __syncthreads();
        #pragma unroll
        for (int i = 0; i < 8; ++i) {
            int idx4 = i * 256 + tid;
            *reinterpret_cast<float4*>(reinterpret_cast<float*>(Wl) + idx4 * 4) =
                *reinterpret_cast<const float4*>(W + kk * 64 * F + idx4 * 4);
        }
        __syncthreads();
        #pragma unroll 2
        for (int k4 = 0; k4 < 64; k4 += 4) {
            float4 w0 = *reinterpret_cast<const float4*>(&Wl[k4 + 0][oq]);
            float4 w1 = *reinterpret_cast<const float4*>(&Wl[k4 + 1][oq]);
            float4 w2 = *reinterpret_cast<const float4*>(&Wl[k4 + 2][oq]);
            float4 w3 = *reinterpret_cast<const float4*>(&Wl[k4 + 3][oq]);
            #pragma unroll
            for (int r = 0; r < 8; ++r) {
                float4 a = *reinterpret_cast<const float4*>(&Al[rg * 8 + r][kk * 64 + k4]);
                FMA4(acc[r], a.x, w0)
                FMA4(acc[r], a.y, w1)
                FMA4(acc[r], a.z, w2)
                FMA4(acc[r], a.w, w3)
            }
        }
    }
    #pragma unroll
    for (int r = 0; r < 8; ++r) {
        int grow = row0 + rg * 8 + r;
        if (grow < NN) {
            float4 a = acc[r];
            __half2 lo = __float22half2_rn(make_float2(a.x, a.y));
            __half2 hi = __float22half2_rn(make_float2(a.z, a.w));
            uint2 pk;
            pk.x = *reinterpret_cast<unsigned*>(&lo);
            pk.y = *reinterpret_cast<unsigned*>(&hi);
            *reinterpret_cast<uint2*>(XW + (size_t)grow * F + oq) = pk;
        }
    }
}

// ---------------- out = relu(A @ XW), fp16 gather, f32 accumulate ----------------
__global__ __launch_bounds__(256) void k_agg_relu(const int* __restrict__ row_ptr,
                                                  const int2* __restrict__ pairs,
                                                  const __half* __restrict__ XW,
                                                  float* __restrict__ out) {
    const int wid  = threadIdx.x >> 6;
    const int lane = threadIdx.x & 63;
    const int node = blockIdx.x * 4 + wid;
    if (node >= NN) return;
    const int p0 = row_ptr[node];
    const int p1 = row_ptr[node + 1];
    const __half* Xl = XW + lane * 2;
    float2 a0 = make_float2(0.f, 0.f), a1 = a0, a2 = a0, a3 = a0;
    int i = p0;
    for (; i + 4 <= p1; i += 4) {
        int2 e0 = pairs[i], e1 = pairs[i + 1], e2 = pairs[i + 2], e3 = pairs[i + 3];
        __half2 h0 = *reinterpret_cast<const __half2*>(Xl + e0.x * F);
        __half2 h1 = *reinterpret_cast<const __half2*>(Xl + e1.x * F);
        __half2 h2 = *reinterpret_cast<const __half2*>(Xl + e2.x * F);
        __half2 h3 = *reinterpret_cast<const __half2*>(Xl + e3.x * F);
        float2 x0 = __half22float2(h0);
        float2 x1 = __half22float2(h1);
        float2 x2 = __half22float2(h2);
        float2 x3 = __half22float2(h3);
        float v0 = __int_as_float(e0.y), v1 = __int_as_float(e1.y);
        float v2 = __int_as_float(e2.y), v3 = __int_as_float(e3.y);
        a0.x += x0.x * v0; a0.y += x0.y * v0;
        a1.x += x1.x * v1; a1.y += x1.y * v1;
        a2.x += x2.x * v2; a2.y += x2.y * v2;
        a3.x += x3.x * v3; a3.y += x3.y * v3;
    }
    for (; i < p1; ++i) {
        int2 e = pairs[i];
        float v = __int_as_float(e.y);
        float2 x = __half22float2(*reinterpret_cast<const __half2*>(Xl + e.x * F));
        a0.x += x.x * v; a0.y += x.y * v;
    }
    float2 r = make_float2((a0.x + a1.x) + (a2.x + a3.x),
                           (a0.y + a1.y) + (a2.y + a3.y));
    r.x = fmaxf(r.x, 0.f);
    r.y = fmaxf(r.y, 0.f);
    *reinterpret_cast<float2*>(out + (size_t)node * F + lane * 2) = r;
}

// ---------------- f32 aggregation (mid fallback) ----------------
__global__ __launch_bounds__(256) void k_agg(const int* __restrict__ row_ptr,
                                             const int2* __restrict__ pairs,
                                             const float* __restrict__ X,
                                             float* __restrict__ agg) {
    const int wid  = threadIdx.x >> 6;
    const int lane = threadIdx.x & 63;
    const int node = blockIdx.x * 4 + wid;
    if (node >= NN) return;
    const int p0 = row_ptr[node];
    const int p1 = row_ptr[node + 1];
    const float* Xl = X + lane * 2;
    float2 a0 = make_float2(0.f, 0.f), a1 = a0, a2 = a0, a3 = a0;
    int i = p0;
    for (; i + 4 <= p1; i += 4) {
        int2 e0 = pairs[i], e1 = pairs[i + 1], e2 = pairs[i + 2], e3 = pairs[i + 3];
        float2 x0 = *reinterpret_cast<const float2*>(Xl + (size_t)e0.x * F);
        float2 x1 = *reinterpret_cast<const float2*>(Xl + (size_t)e1.x * F);
        float2 x2 = *reinterpret_cast<const float2*>(Xl + (size_t)e2.x * F);
        float2 x3 = *reinterpret_cast<const float2*>(Xl + (size_t)e3.x * F);
        float v0 = __int_as_float(e0.y), v1 = __int_as_float(e1.y);
        float v2 = __int_as_float(e2.y), v3 = __int_as_float(e3.y);
        a0.x += x0.x * v0; a0.y += x0.y * v0;
        a1.x += x1.x * v1; a1.y += x1.y * v1;
        a2.x += x2.x * v2; a2.y += x2.y * v2;
        a3.x += x3.x * v3; a3.y += x3.y * v3;
    }
    for (; i < p1; ++i) {
        int2 e = pairs[i];
        float v = __int_as_float(e.y);
        float2 x = *reinterpret_cast<const float2*>(Xl + (size_t)e.x * F);
        a0.x += x.x * v; a0.y += x.y * v;
    }
    float2 r = make_float2((a0.x + a1.x) + (a2.x + a3.x),
                           (a0.y + a1.y) + (a2.y + a3.y));
    *reinterpret_cast<float2*>(agg + (size_t)node * F + lane * 2) = r;
}

// ---------------- in-place GEMM + ReLU (mid fallback) ----------------
__global__ __launch_bounds__(256) void k_gemm_relu(float* __restrict__ io,
                                                   const float* __restrict__ W) {
    __shared__ float Wl[64][128];
    __shared__ float Al[64][128];
    const int tid = threadIdx.x;
    const int rg  = tid >> 5;
    const int oq  = (tid & 31) << 2;
    const int row0 = blockIdx.x * 64;

    #pragma unroll
    for (int i = 0; i < 8; ++i) {
        int idx4 = i * 256 + tid;
        int r  = idx4 >> 5;
        int cc = (idx4 & 31) << 2;
        int grow = row0 + r;
        float4 v = make_float4(0.f, 0.f, 0.f, 0.f);
        if (grow < NN)
            v = *reinterpret_cast<const float4*>(io + (size_t)grow * F + cc);
        *reinterpret_cast<float4*>(&Al[r][cc]) = v;
    }

    float4 acc[8];
    #pragma unroll
    for (int j = 0; j < 8; ++j) acc[j] = make_float4(0.f, 0.f, 0.f, 0.f);

    for (int kk = 0; kk < 2; ++kk) {
        if (kk) __syncthreads();
        #pragma unroll
        for (int i = 0; i < 8; ++i) {
            int idx4 = i * 256 + tid;
            *reinterpret_cast<float4*>(reinterpret_cast<float*>(Wl) + idx4 * 4) =
                *reinterpret_cast<const float4*>(W + kk * 64 * F + idx4 * 4);
        }
        __syncthreads();
        #pragma unroll 2
        for (int k4 = 0; k4 < 64; k4 += 4) {
            float4 w0 = *reinterpret_cast<const float4*>(&Wl[k4 + 0][oq]);
            float4 w1 = *reinterpret_cast<const float4*>(&Wl[k4 + 1][oq]);
            float4 w2 = *reinterpret_cast<const float4*>(&Wl[k4 + 2][oq]);
            float4 w3 = *reinterpret_cast<const float4*>(&Wl[k4 + 3][oq]);
            #pragma unroll
            for (int r = 0; r < 8; ++r) {
                float4 a = *reinterpret_cast<const float4*>(&Al[rg * 8 + r][kk * 64 + k4]);
                FMA4(acc[r], a.x, w0)
                FMA4(acc[r], a.y, w1)
                FMA4(acc[r], a.z, w2)
                FMA4(acc[r], a.w, w3)
            }
        }
    }
    #pragma unroll
    for (int r = 0; r < 8; ++r) {
        int grow = row0 + rg * 8 + r;
        if (grow < NN) {
            float4 a = acc[r];
            a.x = fmaxf(a.x, 0.f);
            a.y = fmaxf(a.y, 0.f);
            a.z = fmaxf(a.z, 0.f);
            a.w = fmaxf(a.w, 0.f);
            *reinterpret_cast<float4*>(io + (size_t)grow * F + oq) = a;
        }
    }
}

// ---------------- legacy atomic scatter (last-resort fallback) ----------------
__global__ void k_zero_f4(float4* __restrict__ p, int n4) {
    int i = blockIdx.x * blockDim.x + threadIdx.x;
    if (i < n4) p[i] = make_float4(0.f, 0.f, 0.f, 0.f);
}

__global__ void k_scatter(const int* __restrict__ erow, const int* __restrict__ ecol,
                          const float* __restrict__ eval, const float* __restrict__ X,
                          float* __restrict__ agg) {
    unsigned tid = blockIdx.x * blockDim.x + threadIdx.x;
    unsigned e = tid >> 5;
    if (e >= NE) return;
    unsigned f = (tid & 31u) << 2;
    int   r = erow[e];
    int   c = ecol[e];
    float v = eval[e];
    float4 x = *reinterpret_cast<const float4*>(X + (size_t)c * F + f);
    float* dst = agg + (size_t)r * F + f;
    atomicAdd(dst + 0, x.x * v);
    atomicAdd(dst + 1, x.y * v);
    atomicAdd(dst + 2, x.z * v);
    atomicAdd(dst + 3, x.w * v);
}

extern "C" void kernel_launch(void* const* d_in, const int* in_sizes, int n_in,
                              void* d_out, int out_size, void* d_ws, size_t ws_size,
                              hipStream_t stream) {
    const int*   erow  = (const int*)d_in[0];
    const int*   ecol  = (const int*)d_in[1];
    const float* evals = (const float*)d_in[2];
    const float* X     = (const float*)d_in[3];
    const float* W     = (const float*)d_in[4];
    float* out = (float*)d_out;

    if (ws_size >= WS_CSR) {
        char* ws = (char*)d_ws;
        int*    cursor  = (int*)(ws + 0);
        int*    row_ptr = (int*)(ws + 200000);
        int*    bsum    = (int*)(ws + 400016);
        int2*   pairs   = (int2*)(ws + 400016);   // overlaps bsum (bsum dead before fill)
        __half* XW      = (__half*)(ws + 5200016);

        k_zero_i<<<(NN + 255) / 256, 256, 0, stream>>>(cursor, NN);
        k_count<<<(NE + 255) / 256, 256, 0, stream>>>(erow, cursor);
        k_bsum<<<NB_SCAN, 256, 0, stream>>>(cursor, bsum);
        k_scan_bsums<<<1, 256, 0, stream>>>(bsum);
        k_scan_final<<<NB_SCAN, 256, 0, stream>>>(cursor, bsum, row_ptr, cursor);
        k_fill<<<(NE + 255) / 256, 256, 0, stream>>>(erow, ecol, evals, cursor, pairs);

        if (ws_size >= WS_FUSED) {
            k_gemm_xw<<<(NN + 63) / 64, 256, 0, stream>>>(X, W, XW);
            k_agg_relu<<<(NN + 3) / 4, 256, 0, stream>>>(row_ptr, pairs, XW, out);
        } else {
            k_agg<<<(NN + 3) / 4, 256, 0, stream>>>(row_ptr, pairs, X, out);
            k_gemm_relu<<<(NN + 63) / 64, 256, 0, stream>>>(out, W);
        }
    } else {
        const int n4 = NN * F / 4;
        k_zero_f4<<<(n4 + 255) / 256, 256, 0, stream>>>((float4*)out, n4);
        k_scatter<<<(NE * 32) / 256, 256, 0, stream>>>(erow, ecol, evals, X, out);
        k_gemm_relu<<<(NN + 63) / 64, 256, 0, stream>>>(out, W);
    }
}